// Round 6
// baseline (194.372 us; speedup 1.0000x reference)
//
#include <hip/hip_runtime.h>
#include <hip/hip_bf16.h>
#include <math.h>

// FFM: B=32768, n=512, f=30, k=40
// inter[b] = X[b]^T W X[b],  W = 0.5*(C - diag(C)), C symmetric
// out = sigmoid(X@w1 + b + inter)
//
// R6: barrier-free K-loop. B fragments load straight from global (L2-hot
// W16) into registers with depth-2 rotation; waves split columns 1x4 so no
// duplicated W traffic. As = 64x512 bf16 XOR-swizzled LDS (read-only after
// Phase A + one barrier). No __syncthreads in the K-loop at all.

#define N_FEAT 512
#define FK 1200
#define KDIM 40
#define B_ROWS 32768
#define BM 64

typedef __attribute__((ext_vector_type(8))) short short8;
typedef __attribute__((ext_vector_type(4))) float f32x4;

__device__ __forceinline__ unsigned short bf16_rne(float f) {
    union { float f; unsigned int u; } c; c.f = f;
    unsigned int u = c.u;
    u += 0x7fffu + ((u >> 16) & 1u);
    return (unsigned short)(u >> 16);
}

__device__ __forceinline__ float bf16_to_f(unsigned short h) {
    union { unsigned int u; float f; } c;
    c.u = ((unsigned int)h) << 16;
    return c.f;
}

// ---------------- Kernel 1: build W16 (512x512 bf16) ----------------
__global__ __launch_bounds__(256) void build_w16(const float* __restrict__ v,
                                                 const int* __restrict__ f2f,
                                                 unsigned short* __restrict__ W16) {
    const int j = blockIdx.x * 256 + threadIdx.x;
    const int i = blockIdx.y;
    const int fi = f2f[i];
    const int fj = f2f[j];
    const float4* a = (const float4*)(v + (size_t)i * FK + (size_t)fj * KDIM);
    const float4* c = (const float4*)(v + (size_t)j * FK + (size_t)fi * KDIM);
    float acc = 0.f;
#pragma unroll
    for (int q = 0; q < KDIM / 4; ++q) {
        float4 av = a[q], cv = c[q];
        acc = fmaf(av.x, cv.x, acc);
        acc = fmaf(av.y, cv.y, acc);
        acc = fmaf(av.z, cv.z, acc);
        acc = fmaf(av.w, cv.w, acc);
    }
    W16[(size_t)i * N_FEAT + j] = (i == j) ? (unsigned short)0 : bf16_rne(0.5f * acc);
}

// ---------------- Kernel 2: fused GEMM + quadratic-form epilogue ----------------
// grid: 512 blocks x 256 threads (4 waves). Wave w covers cols cb*128 + w*32
// (ni=0..1 sixteens), all 64 rows (mi=0..3). B frags from global, no LDS Bs.
__global__ __launch_bounds__(256, 2) void ffm_fused(const float* __restrict__ X,
                                                    const unsigned short* __restrict__ W16,
                                                    const float* __restrict__ w1,
                                                    const float* __restrict__ bvec,
                                                    float* __restrict__ out) {
    __shared__ __align__(16) unsigned short As[BM * N_FEAT];  // 64 KB, swizzled
    __shared__ float part[4][BM];                              // 1 KB

    const int tid  = threadIdx.x;
    const int lane = tid & 63;
    const int wave = tid >> 6;
    const int quad = lane >> 4;
    const int l16  = lane & 15;
    const int aswz = l16 & 7;

    const size_t row0 = (size_t)blockIdx.x * BM;

    // ---- Phase A: stage As = bf16(X[row0 : row0+64][0:512]), swizzled chunks ----
    {
        const float4* X4 = (const float4*)(X + row0 * N_FEAT);
#pragma unroll
        for (int u = 0; u < 16; ++u) {
            const int g  = u * 256 + tid;
            const int r  = g >> 6;          // 0..63
            const int cc = g & 63;          // 16B chunk in row
            float4 f0 = X4[r * 128 + cc * 2];
            float4 f1 = X4[r * 128 + cc * 2 + 1];
            union { unsigned short us[8]; short8 v; } pk;
            pk.us[0] = bf16_rne(f0.x);
            pk.us[1] = bf16_rne(f0.y);
            pk.us[2] = bf16_rne(f0.z);
            pk.us[3] = bf16_rne(f0.w);
            pk.us[4] = bf16_rne(f1.x);
            pk.us[5] = bf16_rne(f1.y);
            pk.us[6] = bf16_rne(f1.z);
            pk.us[7] = bf16_rne(f1.w);
            *(short8*)(As + r * N_FEAT + ((cc ^ (r & 7)) << 3)) = pk.v;
        }
    }
    __syncthreads();   // the only pre-epilogue barrier

    float rs[4][4];
#pragma unroll
    for (int mi = 0; mi < 4; ++mi)
#pragma unroll
        for (int reg = 0; reg < 4; ++reg) rs[mi][reg] = 0.f;

    for (int cb = 0; cb < 4; ++cb) {
        const int colw = cb * 128 + wave * 32;            // this wave's 32-col base
        // lane's W16 base: row (colw + l16), k-offset quad*8
        const unsigned short* wptr =
            W16 + (((size_t)(colw + l16)) << 9) + (quad << 3);

        f32x4 acc[4][2];
#pragma unroll
        for (int mi = 0; mi < 4; ++mi)
#pragma unroll
            for (int ni = 0; ni < 2; ++ni)
                acc[mi][ni] = (f32x4){0.f, 0.f, 0.f, 0.f};

        short8 bcur[2], bnxt[2];
        bcur[0] = *(const short8*)(wptr);
        bcur[1] = *(const short8*)(wptr + 16 * N_FEAT);

#pragma unroll
        for (int ks = 0; ks < 16; ++ks) {
            if (ks < 15) {
                bnxt[0] = *(const short8*)(wptr + (ks + 1) * 32);
                bnxt[1] = *(const short8*)(wptr + 16 * N_FEAT + (ks + 1) * 32);
            }
            short8 a[4];
            const int kc = ks * 4 + quad;                 // 16B chunk idx 0..63
            const int off = ((kc ^ aswz) << 3);
#pragma unroll
            for (int mi = 0; mi < 4; ++mi)
                a[mi] = *(const short8*)(As + (mi * 16 + l16) * N_FEAT + off);
#pragma unroll
            for (int mi = 0; mi < 4; ++mi)
#pragma unroll
                for (int ni = 0; ni < 2; ++ni)
                    acc[mi][ni] = __builtin_amdgcn_mfma_f32_16x16x32_bf16(
                        a[mi], bcur[ni], acc[mi][ni], 0, 0, 0);
            bcur[0] = bnxt[0];
            bcur[1] = bnxt[1];
        }

        // Epilogue for this col-block: rs += x_hat * (y + w1), x_hat from As.
        float w1v[2];
#pragma unroll
        for (int ni = 0; ni < 2; ++ni)
            w1v[ni] = w1[colw + ni * 16 + l16];
#pragma unroll
        for (int mi = 0; mi < 4; ++mi) {
#pragma unroll
            for (int ni = 0; ni < 2; ++ni) {
                const int gc = colw + ni * 16 + l16;      // global col 0..511
#pragma unroll
                for (int reg = 0; reg < 4; ++reg) {
                    const int row = mi * 16 + quad * 4 + reg;
                    const int adr = row * N_FEAT +
                                    ((((gc >> 3) ^ (row & 7)) << 3) | (gc & 7));
                    const float xf = bf16_to_f(As[adr]);
                    rs[mi][reg] = fmaf(xf, acc[mi][ni][reg] + w1v[ni], rs[mi][reg]);
                }
            }
        }
    }

    // Reduce over l16 within each quad, then across the 4 waves via LDS.
#pragma unroll
    for (int mi = 0; mi < 4; ++mi)
#pragma unroll
        for (int reg = 0; reg < 4; ++reg) {
            float r = rs[mi][reg];
#pragma unroll
            for (int off = 1; off < 16; off <<= 1)
                r += __shfl_xor(r, off, 16);
            if (l16 == 0)
                part[wave][mi * 16 + quad * 4 + reg] = r;
        }
    __syncthreads();

    if (tid < BM) {
        const float t = part[0][tid] + part[1][tid] + part[2][tid] + part[3][tid]
                        + bvec[0];
        out[row0 + tid] = 1.0f / (1.0f + expf(-t));
    }
}

extern "C" void kernel_launch(void* const* d_in, const int* in_sizes, int n_in,
                              void* d_out, int out_size, void* d_ws, size_t ws_size,
                              hipStream_t stream) {
    const float* X   = (const float*)d_in[0];   // 32768 x 512
    const float* w1  = (const float*)d_in[1];   // 512
    const float* b   = (const float*)d_in[2];   // 1
    const float* v   = (const float*)d_in[3];   // 512 x 30 x 40
    const int*   f2f = (const int*)d_in[4];     // 512
    float* out = (float*)d_out;                 // 32768

    unsigned short* W16 = (unsigned short*)d_ws;   // 512 KB scratch

    build_w16<<<dim3(2, N_FEAT), 256, 0, stream>>>(v, f2f, W16);
    ffm_fused<<<B_ROWS / BM, 256, 0, stream>>>(X, W16, w1, b, out);
}

// Round 7
// 153.613 us; speedup vs baseline: 1.2653x; 1.2653x over previous
//
#include <hip/hip_runtime.h>
#include <hip/hip_bf16.h>
#include <math.h>

// FFM: B=32768, n=512, f=30, k=40
// inter[b] = X[b]^T W X[b],  W = 0.5*(C - diag(C)), C symmetric
// out = sigmoid(X@w1 + b + inter)
//
// R7: R5 skeleton (As = 64x512 bf16 full-K resident, swizzled; Bs streamed)
// + software-pipelined K-loop: 4 rotating Bs buffers, 2-deep prefetch via
// global_load_lds, manual `s_waitcnt vmcnt(8)` + raw s_barrier (never a
// full drain in steady state). Linear term x.w1 computed in fp32 during
// Phase A (wave reduction) so the K-loop has zero extra vmem ops.

#define N_FEAT 512
#define FK 1200
#define KDIM 40
#define B_ROWS 32768
#define BM 64

typedef __attribute__((ext_vector_type(8))) short short8;
typedef __attribute__((ext_vector_type(4))) float f32x4;

__device__ __forceinline__ unsigned short bf16_rne(float f) {
    union { float f; unsigned int u; } c; c.f = f;
    unsigned int u = c.u;
    u += 0x7fffu + ((u >> 16) & 1u);
    return (unsigned short)(u >> 16);
}

__device__ __forceinline__ float bf16_to_f(unsigned short h) {
    union { unsigned int u; float f; } c;
    c.u = ((unsigned int)h) << 16;
    return c.f;
}

__device__ __forceinline__ void async_copy16(const void* g, void* l) {
    __builtin_amdgcn_global_load_lds(
        (const __attribute__((address_space(1))) void*)g,
        (__attribute__((address_space(3))) void*)l,
        16, 0, 0);
}

// ---------------- Kernel 1: build W16 (512x512 bf16) ----------------
__global__ __launch_bounds__(256) void build_w16(const float* __restrict__ v,
                                                 const int* __restrict__ f2f,
                                                 unsigned short* __restrict__ W16) {
    const int j = blockIdx.x * 256 + threadIdx.x;
    const int i = blockIdx.y;
    const int fi = f2f[i];
    const int fj = f2f[j];
    const float4* a = (const float4*)(v + (size_t)i * FK + (size_t)fj * KDIM);
    const float4* c = (const float4*)(v + (size_t)j * FK + (size_t)fi * KDIM);
    float acc = 0.f;
#pragma unroll
    for (int q = 0; q < KDIM / 4; ++q) {
        float4 av = a[q], cv = c[q];
        acc = fmaf(av.x, cv.x, acc);
        acc = fmaf(av.y, cv.y, acc);
        acc = fmaf(av.z, cv.z, acc);
        acc = fmaf(av.w, cv.w, acc);
    }
    W16[(size_t)i * N_FEAT + j] = (i == j) ? (unsigned short)0 : bf16_rne(0.5f * acc);
}

// ---------------- Kernel 2: fused GEMM + quadratic-form epilogue ----------------
// grid: 512 blocks x 256 threads (4 waves, 2x2: wm rows-half, wn cols-half).
__global__ __launch_bounds__(256, 1) void ffm_fused(const float* __restrict__ X,
                                                    const unsigned short* __restrict__ W16,
                                                    const float* __restrict__ w1,
                                                    const float* __restrict__ bvec,
                                                    float* __restrict__ out) {
    __shared__ __align__(16) unsigned short As[BM * N_FEAT];   // 64 KB
    __shared__ __align__(16) unsigned short Bs[4][128 * 64];   // 4 x 16 KB
    __shared__ float part[2][BM];
    __shared__ float plin[BM];

    const int tid  = threadIdx.x;
    const int lane = tid & 63;
    const int wave = tid >> 6;
    const int wm = wave & 1;
    const int wn = wave >> 1;
    const int quad = lane >> 4;
    const int l16  = lane & 15;
    const int aswz = l16 & 7;

    const size_t row0 = (size_t)blockIdx.x * BM;

    // ---- Phase A: stage As (swizzled) + fp32 linear term per row ----
    {
        const float4* X4 = (const float4*)(X + row0 * N_FEAT);
        const float4 wA = ((const float4*)w1)[lane * 2];
        const float4 wB = ((const float4*)w1)[lane * 2 + 1];
#pragma unroll
        for (int u = 0; u < 16; ++u) {
            const int r  = u * 4 + wave;    // wave-uniform row
            const int cc = lane;            // 16B chunk in row
            float4 f0 = X4[r * 128 + cc * 2];
            float4 f1 = X4[r * 128 + cc * 2 + 1];
            union { unsigned short us[8]; short8 v; } pk;
            pk.us[0] = bf16_rne(f0.x);
            pk.us[1] = bf16_rne(f0.y);
            pk.us[2] = bf16_rne(f0.z);
            pk.us[3] = bf16_rne(f0.w);
            pk.us[4] = bf16_rne(f1.x);
            pk.us[5] = bf16_rne(f1.y);
            pk.us[6] = bf16_rne(f1.z);
            pk.us[7] = bf16_rne(f1.w);
            *(short8*)(As + r * N_FEAT + ((cc ^ (r & 7)) << 3)) = pk.v;
            // linear-term partial: dot(x[r][cc*8..+8], w1[cc*8..+8])
            float lp = f0.x * wA.x + f0.y * wA.y + f0.z * wA.z + f0.w * wA.w
                     + f1.x * wB.x + f1.y * wB.y + f1.z * wB.z + f1.w * wB.w;
#pragma unroll
            for (int off = 1; off < 64; off <<= 1)
                lp += __shfl_xor(lp, off, 64);
            if (lane == 0) plin[r] = lp;
        }
    }
    __syncthreads();

    const int srow = lane >> 3;
    const int scol = ((lane & 7) ^ srow) << 3;

    float rs[2][4];
    f32x4 acc[2][4];
#pragma unroll
    for (int mi = 0; mi < 2; ++mi)
#pragma unroll
        for (int ni = 0; ni < 4; ++ni) {
            acc[mi][ni] = (f32x4){0.f, 0.f, 0.f, 0.f};
            if (ni < 4) {}
        }
#pragma unroll
    for (int mi = 0; mi < 2; ++mi)
#pragma unroll
        for (int reg = 0; reg < 4; ++reg) rs[mi][reg] = 0.f;

    // step t: cb = t>>3, k0 = (t&7)*64, buffer t&3
    auto stage = [&](int t) {
        unsigned short* buf = &Bs[t & 3][0];
        const int col0 = (t >> 3) * 128;
        const int k0   = (t & 7) * 64;
#pragma unroll
        for (int c = 0; c < 4; ++c) {
            const int chunk = wave * 4 + c;          // 0..15, 1 KB each
            const int r = chunk * 8 + srow;          // Bs row 0..127
            async_copy16(W16 + (size_t)(col0 + r) * N_FEAT + k0 + scol,
                         buf + chunk * 512);
        }
    };

    auto compute = [&](int t) {
        const unsigned short* buf = &Bs[t & 3][0];
        const int k0 = (t & 7) * 64;
#pragma unroll
        for (int kk = 0; kk < 2; ++kk) {
            short8 a[2], b[4];
            const int kc = (k0 >> 3) + kk * 4 + quad;
#pragma unroll
            for (int mi = 0; mi < 2; ++mi) {
                const int ar = wm * 32 + mi * 16 + l16;
                a[mi] = *(const short8*)(As + ar * N_FEAT + ((kc ^ aswz) << 3));
            }
            const int swc = ((kk * 4 + quad) ^ aswz) << 3;
#pragma unroll
            for (int ni = 0; ni < 4; ++ni) {
                const int br = wn * 64 + ni * 16 + l16;
                b[ni] = *(const short8*)(buf + br * 64 + swc);
            }
#pragma unroll
            for (int mi = 0; mi < 2; ++mi)
#pragma unroll
                for (int ni = 0; ni < 4; ++ni)
                    acc[mi][ni] = __builtin_amdgcn_mfma_f32_16x16x32_bf16(
                        a[mi], b[ni], acc[mi][ni], 0, 0, 0);
        }
    };

    auto epilogue = [&](int cb) {
#pragma unroll
        for (int mi = 0; mi < 2; ++mi) {
#pragma unroll
            for (int ni = 0; ni < 4; ++ni) {
                const int gc = cb * 128 + wn * 64 + ni * 16 + l16;
#pragma unroll
                for (int reg = 0; reg < 4; ++reg) {
                    const int row = wm * 32 + mi * 16 + quad * 4 + reg;
                    const int adr = row * N_FEAT +
                                    ((((gc >> 3) ^ (row & 7)) << 3) | (gc & 7));
                    rs[mi][reg] = fmaf(bf16_to_f(As[adr]), acc[mi][ni][reg],
                                       rs[mi][reg]);
                }
                acc[mi][ni] = (f32x4){0.f, 0.f, 0.f, 0.f};
            }
        }
    };

    // ---- pipelined K-loop: 32 steps, 2-deep prefetch, partial-drain barriers ----
    stage(0);
    stage(1);
    for (int s = 0; s < 30; ++s) {
        stage(s + 2);
        asm volatile("s_waitcnt vmcnt(8)" ::: "memory");   // stage(s) landed
        __builtin_amdgcn_s_barrier();
        compute(s);
        if ((s & 7) == 7) epilogue(s >> 3);
    }
    asm volatile("s_waitcnt vmcnt(4)" ::: "memory");       // stage(30) landed
    __builtin_amdgcn_s_barrier();
    compute(30);
    asm volatile("s_waitcnt vmcnt(0)" ::: "memory");       // stage(31) landed
    __builtin_amdgcn_s_barrier();
    compute(31);
    epilogue(3);

    // ---- reduce + bias + sigmoid ----
#pragma unroll
    for (int mi = 0; mi < 2; ++mi)
#pragma unroll
        for (int reg = 0; reg < 4; ++reg) {
            float r = rs[mi][reg];
#pragma unroll
            for (int off = 1; off < 16; off <<= 1)
                r += __shfl_xor(r, off, 16);
            if (l16 == 0)
                part[wn][wm * 32 + mi * 16 + quad * 4 + reg] = r;
        }
    __syncthreads();

    if (tid < BM) {
        const float t = part[0][tid] + part[1][tid] + plin[tid] + bvec[0];
        out[row0 + tid] = 1.0f / (1.0f + expf(-t));
    }
}

extern "C" void kernel_launch(void* const* d_in, const int* in_sizes, int n_in,
                              void* d_out, int out_size, void* d_ws, size_t ws_size,
                              hipStream_t stream) {
    const float* X   = (const float*)d_in[0];   // 32768 x 512
    const float* w1  = (const float*)d_in[1];   // 512
    const float* b   = (const float*)d_in[2];   // 1
    const float* v   = (const float*)d_in[3];   // 512 x 30 x 40
    const int*   f2f = (const int*)d_in[4];     // 512
    float* out = (float*)d_out;                 // 32768

    unsigned short* W16 = (unsigned short*)d_ws;   // 512 KB scratch

    build_w16<<<dim3(2, N_FEAT), 256, 0, stream>>>(v, f2f, W16);
    ffm_fused<<<B_ROWS / BM, 256, 0, stream>>>(X, W16, w1, b, out);
}